// Round 1
// baseline (6444.149 us; speedup 1.0000x reference)
//
#include <hip/hip_runtime.h>
#include <math.h>

#define NUSER 100000
#define NITEM 100000
#define NEDGE 800000
#define DIN 128
#define HD 256
#define TM 16

using f4 = __attribute__((ext_vector_type(4))) float;

__device__ __forceinline__ float gelu_f(float x) {
    return 0.5f * x * (1.0f + erff(x * 0.70710678118654752440f));
}

// ---------------- CSR build ----------------
__global__ void k_hist(const int* __restrict__ dst, int* __restrict__ cnt, int n) {
    for (int i = blockIdx.x * blockDim.x + threadIdx.x; i < n; i += gridDim.x * blockDim.x)
        atomicAdd(&cnt[dst[i]], 1);
}

// one block per (cnt, rp, cur) set; block 0 = items, block 1 = users
__global__ __launch_bounds__(1024) void k_scan2(
    const int* __restrict__ cnt0, int* __restrict__ rp0, int* __restrict__ cur0, int n0,
    const int* __restrict__ cnt1, int* __restrict__ rp1, int* __restrict__ cur1, int n1) {
    const int* cnt = (blockIdx.x == 0) ? cnt0 : cnt1;
    int* rp  = (blockIdx.x == 0) ? rp0  : rp1;
    int* cur = (blockIdx.x == 0) ? cur0 : cur1;
    int n    = (blockIdx.x == 0) ? n0   : n1;

    __shared__ int buf[1024];
    const int t = threadIdx.x;
    int carry = 0;
    for (int base = 0; base < n; base += 1024) {
        int i = base + t;
        int v = (i < n) ? cnt[i] : 0;
        buf[t] = v;
        __syncthreads();
        for (int off = 1; off < 1024; off <<= 1) {
            int add = (t >= off) ? buf[t - off] : 0;
            __syncthreads();
            buf[t] += add;
            __syncthreads();
        }
        int incl  = buf[t];
        int total = buf[1023];
        if (i < n) { int ex = carry + incl - v; rp[i] = ex; cur[i] = ex; }
        carry += total;
        __syncthreads();
    }
    if (t == 0) rp[n] = carry;
}

__global__ void k_scatter(const int* __restrict__ src, const int* __restrict__ dst,
                          int* __restrict__ cur, int* __restrict__ sl, int n) {
    for (int i = blockIdx.x * blockDim.x + threadIdx.x; i < n; i += gridDim.x * blockDim.x) {
        int p = atomicAdd(&cur[dst[i]], 1);
        sl[p] = src[i];
    }
}

// ---------------- input projection: out = GELU(X @ W + b), X:[M,128], W:[128,256] ----------------
__global__ __launch_bounds__(256) void k_proj(const float* __restrict__ X,
        const float* __restrict__ W, const float* __restrict__ b,
        float* __restrict__ out) {
    __shared__ __align__(16) float A[TM][DIN];
    const int t = threadIdx.x;
    const int w = t >> 6, l = t & 63;
    const int r0 = blockIdx.x * TM;
    const int c0 = 4 * l;

    // stage 16 rows of X (128 f32 each): wave w handles rows w, w+4, w+8, w+12
    #pragma unroll
    for (int i = 0; i < 4; ++i) {
        int r = w + 4 * i;
        const float2 v = *(const float2*)&X[(size_t)(r0 + r) * DIN + 2 * l];
        *(float2*)&A[r][2 * l] = v;
    }
    __syncthreads();

    f4 acc[4] = {{0,0,0,0},{0,0,0,0},{0,0,0,0},{0,0,0,0}};
    for (int k = 0; k < DIN; k += 4) {
        f4 w0 = *(const f4*)&W[(size_t)(k + 0) * HD + c0];
        f4 w1 = *(const f4*)&W[(size_t)(k + 1) * HD + c0];
        f4 w2 = *(const f4*)&W[(size_t)(k + 2) * HD + c0];
        f4 w3 = *(const f4*)&W[(size_t)(k + 3) * HD + c0];
        #pragma unroll
        for (int i = 0; i < 4; ++i) {
            f4 av = *(const f4*)&A[4 * w + i][k];
            acc[i] += av.x * w0 + av.y * w1 + av.z * w2 + av.w * w3;
        }
    }
    f4 bias = *(const f4*)&b[c0];
    #pragma unroll
    for (int i = 0; i < 4; ++i) {
        f4 v = acc[i] + bias;
        v.x = gelu_f(v.x); v.y = gelu_f(v.y); v.z = gelu_f(v.z); v.w = gelu_f(v.w);
        *(f4*)&out[(size_t)(r0 + 4 * w + i) * HD + c0] = v;
    }
}

// ---------------- SAGE conv: out = GELU(mean_gather(hsrc) @ Wl + bl + hdst @ Wr) ----------------
__global__ __launch_bounds__(256) void k_conv(const float* __restrict__ hsrc,
        const float* __restrict__ hdst, const int* __restrict__ rp, const int* __restrict__ sl,
        const float* __restrict__ Wl, const float* __restrict__ bl, const float* __restrict__ Wr,
        float* __restrict__ out) {
    __shared__ __align__(16) float A[TM][2 * HD];  // [r][0..255]=agg, [r][256..511]=root
    const int t = threadIdx.x;
    const int w = t >> 6, l = t & 63;
    const int r0 = blockIdx.x * TM;
    const int c0 = 4 * l;

    // stage: fused CSR mean-gather + root copy. wave w handles rows w, w+4, w+8, w+12
    for (int i = 0; i < 4; ++i) {
        int r = w + 4 * i;
        int gr = r0 + r;
        f4 acc = {0, 0, 0, 0};
        int beg = rp[gr], end = rp[gr + 1];
        int e = beg;
        for (; e + 4 <= end; e += 4) {   // 4 outstanding loads to hide L3 latency
            int s0 = sl[e], s1 = sl[e + 1], s2 = sl[e + 2], s3 = sl[e + 3];
            f4 v0 = *(const f4*)&hsrc[(size_t)s0 * HD + c0];
            f4 v1 = *(const f4*)&hsrc[(size_t)s1 * HD + c0];
            f4 v2 = *(const f4*)&hsrc[(size_t)s2 * HD + c0];
            f4 v3 = *(const f4*)&hsrc[(size_t)s3 * HD + c0];
            acc += (v0 + v1) + (v2 + v3);
        }
        for (; e < end; ++e)
            acc += *(const f4*)&hsrc[(size_t)sl[e] * HD + c0];
        float inv = 1.0f / fmaxf((float)(end - beg), 1.0f);
        acc *= inv;
        *(f4*)&A[r][c0] = acc;
        *(f4*)&A[r][HD + c0] = *(const f4*)&hdst[(size_t)gr * HD + c0];
    }
    __syncthreads();

    // GEMM: thread (w,l) computes rows 4w..4w+3 x cols 4l..4l+3, K=512
    f4 acc[4] = {{0,0,0,0},{0,0,0,0},{0,0,0,0},{0,0,0,0}};
    for (int k = 0; k < HD; k += 4) {
        f4 w0 = *(const f4*)&Wl[(size_t)(k + 0) * HD + c0];
        f4 w1 = *(const f4*)&Wl[(size_t)(k + 1) * HD + c0];
        f4 w2 = *(const f4*)&Wl[(size_t)(k + 2) * HD + c0];
        f4 w3 = *(const f4*)&Wl[(size_t)(k + 3) * HD + c0];
        #pragma unroll
        for (int i = 0; i < 4; ++i) {
            f4 av = *(const f4*)&A[4 * w + i][k];
            acc[i] += av.x * w0 + av.y * w1 + av.z * w2 + av.w * w3;
        }
    }
    for (int k = 0; k < HD; k += 4) {
        f4 w0 = *(const f4*)&Wr[(size_t)(k + 0) * HD + c0];
        f4 w1 = *(const f4*)&Wr[(size_t)(k + 1) * HD + c0];
        f4 w2 = *(const f4*)&Wr[(size_t)(k + 2) * HD + c0];
        f4 w3 = *(const f4*)&Wr[(size_t)(k + 3) * HD + c0];
        #pragma unroll
        for (int i = 0; i < 4; ++i) {
            f4 av = *(const f4*)&A[4 * w + i][HD + k];
            acc[i] += av.x * w0 + av.y * w1 + av.z * w2 + av.w * w3;
        }
    }
    f4 bias = *(const f4*)&bl[c0];
    #pragma unroll
    for (int i = 0; i < 4; ++i) {
        f4 v = acc[i] + bias;
        v.x = gelu_f(v.x); v.y = gelu_f(v.y); v.z = gelu_f(v.z); v.w = gelu_f(v.w);
        *(f4*)&out[(size_t)(r0 + 4 * w + i) * HD + c0] = v;
    }
}

// ---------------- head: out = LayerNorm(H @ W + b) * g + b2 ----------------
__global__ __launch_bounds__(256) void k_head(const float* __restrict__ Hin,
        const float* __restrict__ W, const float* __restrict__ b,
        const float* __restrict__ g, const float* __restrict__ b2,
        float* __restrict__ out) {
    __shared__ __align__(16) float A[TM][HD];
    const int t = threadIdx.x;
    const int w = t >> 6, l = t & 63;
    const int r0 = blockIdx.x * TM;
    const int c0 = 4 * l;

    #pragma unroll
    for (int i = 0; i < 4; ++i) {
        int r = w + 4 * i;
        *(f4*)&A[r][c0] = *(const f4*)&Hin[(size_t)(r0 + r) * HD + c0];
    }
    __syncthreads();

    f4 acc[4] = {{0,0,0,0},{0,0,0,0},{0,0,0,0},{0,0,0,0}};
    for (int k = 0; k < HD; k += 4) {
        f4 w0 = *(const f4*)&W[(size_t)(k + 0) * HD + c0];
        f4 w1 = *(const f4*)&W[(size_t)(k + 1) * HD + c0];
        f4 w2 = *(const f4*)&W[(size_t)(k + 2) * HD + c0];
        f4 w3 = *(const f4*)&W[(size_t)(k + 3) * HD + c0];
        #pragma unroll
        for (int i = 0; i < 4; ++i) {
            f4 av = *(const f4*)&A[4 * w + i][k];
            acc[i] += av.x * w0 + av.y * w1 + av.z * w2 + av.w * w3;
        }
    }

    f4 bias = *(const f4*)&b[c0];
    f4 gv   = *(const f4*)&g[c0];
    f4 bv   = *(const f4*)&b2[c0];
    // LayerNorm per row; wave w owns rows 4w..4w+3, cols spread across its 64 lanes
    #pragma unroll
    for (int i = 0; i < 4; ++i) {
        f4 v = acc[i] + bias;
        float s = v.x + v.y + v.z + v.w;
        #pragma unroll
        for (int off = 32; off > 0; off >>= 1) s += __shfl_xor(s, off, 64);
        float mu = s * (1.0f / HD);
        f4 d = v - mu;
        float q = d.x * d.x + d.y * d.y + d.z * d.z + d.w * d.w;
        #pragma unroll
        for (int off = 32; off > 0; off >>= 1) q += __shfl_xor(q, off, 64);
        float rs = rsqrtf(q * (1.0f / HD) + 1e-5f);
        f4 o = d * rs * gv + bv;
        *(f4*)&out[(size_t)(r0 + 4 * w + i) * HD + c0] = o;
    }
}

extern "C" void kernel_launch(void* const* d_in, const int* in_sizes, int n_in,
                              void* d_out, int out_size, void* d_ws, size_t ws_size,
                              hipStream_t stream) {
    const float* x_user     = (const float*)d_in[0];
    const float* x_item     = (const float*)d_in[1];
    const int*   ei_ui_src  = (const int*)d_in[2];
    const int*   ei_ui_dst  = (const int*)d_in[3];
    const int*   ei_iu_src  = (const int*)d_in[4];
    const int*   ei_iu_dst  = (const int*)d_in[5];
    const float* lin_user_W = (const float*)d_in[6];
    const float* lin_user_b = (const float*)d_in[7];
    const float* lin_item_W = (const float*)d_in[8];
    const float* lin_item_b = (const float*)d_in[9];
    const float* c0_ui_Wl = (const float*)d_in[10];
    const float* c0_ui_bl = (const float*)d_in[11];
    const float* c0_ui_Wr = (const float*)d_in[12];
    const float* c0_iu_Wl = (const float*)d_in[13];
    const float* c0_iu_bl = (const float*)d_in[14];
    const float* c0_iu_Wr = (const float*)d_in[15];
    const float* c1_ui_Wl = (const float*)d_in[16];
    const float* c1_ui_bl = (const float*)d_in[17];
    const float* c1_ui_Wr = (const float*)d_in[18];
    const float* c1_iu_Wl = (const float*)d_in[19];
    const float* c1_iu_bl = (const float*)d_in[20];
    const float* c1_iu_Wr = (const float*)d_in[21];
    const float* out_user_W = (const float*)d_in[22];
    const float* out_user_b = (const float*)d_in[23];
    const float* out_item_W = (const float*)d_in[24];
    const float* out_item_b = (const float*)d_in[25];
    const float* ln_user_g  = (const float*)d_in[26];
    const float* ln_user_b2 = (const float*)d_in[27];
    const float* ln_item_g  = (const float*)d_in[28];
    const float* ln_item_b2 = (const float*)d_in[29];

    char* ws = (char*)d_ws;
    size_t off = 0;
    auto alloc = [&](size_t bytes) -> void* {
        void* p = ws + off;
        off += (bytes + 255) & ~(size_t)255;
        return p;
    };
    float* Au   = (float*)alloc((size_t)NUSER * HD * 4);   // h_user ping
    float* Ai   = (float*)alloc((size_t)NITEM * HD * 4);   // h_item ping
    int* rp_i   = (int*)alloc((NITEM + 1) * 4);            // CSR row_ptr, dst=item (ui edges)
    int* rp_u   = (int*)alloc((NUSER + 1) * 4);            // CSR row_ptr, dst=user (iu edges)
    int* cur_i  = (int*)alloc(NITEM * 4);
    int* cur_u  = (int*)alloc(NUSER * 4);
    int* cnt_i  = (int*)alloc(NITEM * 4);
    int* cnt_u  = (int*)alloc(NUSER * 4);
    int* sl_ui  = (int*)alloc((size_t)NEDGE * 4);          // src (user) sorted by dst item
    int* sl_iu  = (int*)alloc((size_t)NEDGE * 4);          // src (item) sorted by dst user

    // h pong buffers live in d_out (fully overwritten by the heads at the end)
    float* Bu = (float*)d_out;
    float* Bi = (float*)d_out + (size_t)NUSER * HD;

    // ---- CSR build (identical work every call; ws is re-poisoned each call) ----
    hipMemsetAsync(cnt_i, 0, NITEM * 4, stream);
    hipMemsetAsync(cnt_u, 0, NUSER * 4, stream);
    k_hist<<<1024, 256, 0, stream>>>(ei_ui_dst, cnt_i, NEDGE);
    k_hist<<<1024, 256, 0, stream>>>(ei_iu_dst, cnt_u, NEDGE);
    k_scan2<<<2, 1024, 0, stream>>>(cnt_i, rp_i, cur_i, NITEM, cnt_u, rp_u, cur_u, NUSER);
    k_scatter<<<1024, 256, 0, stream>>>(ei_ui_src, ei_ui_dst, cur_i, sl_ui, NEDGE);
    k_scatter<<<1024, 256, 0, stream>>>(ei_iu_src, ei_iu_dst, cur_u, sl_iu, NEDGE);

    // ---- input projections ----
    k_proj<<<NUSER / TM, 256, 0, stream>>>(x_user, lin_user_W, lin_user_b, Au);
    k_proj<<<NITEM / TM, 256, 0, stream>>>(x_item, lin_item_W, lin_item_b, Ai);

    // ---- layer 0 (reads A*, writes B*) ----
    k_conv<<<NITEM / TM, 256, 0, stream>>>(Au, Ai, rp_i, sl_ui, c0_ui_Wl, c0_ui_bl, c0_ui_Wr, Bi);
    k_conv<<<NUSER / TM, 256, 0, stream>>>(Ai, Au, rp_u, sl_iu, c0_iu_Wl, c0_iu_bl, c0_iu_Wr, Bu);

    // ---- layer 1 (reads B*, writes A*) ----
    k_conv<<<NITEM / TM, 256, 0, stream>>>(Bu, Bi, rp_i, sl_ui, c1_ui_Wl, c1_ui_bl, c1_ui_Wr, Ai);
    k_conv<<<NUSER / TM, 256, 0, stream>>>(Bi, Bu, rp_u, sl_iu, c1_iu_Wl, c1_iu_bl, c1_iu_Wr, Au);

    // ---- heads + LayerNorm (reads A*, writes d_out; B* no longer needed) ----
    k_head<<<NUSER / TM, 256, 0, stream>>>(Au, out_user_W, out_user_b, ln_user_g, ln_user_b2,
                                           (float*)d_out);
    k_head<<<NITEM / TM, 256, 0, stream>>>(Ai, out_item_W, out_item_b, ln_item_g, ln_item_b2,
                                           (float*)d_out + (size_t)NUSER * HD);
}

// Round 2
// 3738.205 us; speedup vs baseline: 1.7239x; 1.7239x over previous
//
#include <hip/hip_runtime.h>
#include <math.h>

#define NUSER 100000
#define NITEM 100000
#define NEDGE 800000
#define DIN 128
#define HD 256
#define TM 16

using f4 = __attribute__((ext_vector_type(4))) float;

__device__ __forceinline__ float gelu_f(float x) {
    return 0.5f * x * (1.0f + erff(x * 0.70710678118654752440f));
}

// ---------------- CSR build ----------------
__global__ void k_hist(const int* __restrict__ dst, int* __restrict__ cnt, int n) {
    for (int i = blockIdx.x * blockDim.x + threadIdx.x; i < n; i += gridDim.x * blockDim.x)
        atomicAdd(&cnt[dst[i]], 1);
}

// one block per (cnt, rp, cur) set; block 0 = items, block 1 = users
__global__ __launch_bounds__(1024) void k_scan2(
    const int* __restrict__ cnt0, int* __restrict__ rp0, int* __restrict__ cur0, int n0,
    const int* __restrict__ cnt1, int* __restrict__ rp1, int* __restrict__ cur1, int n1) {
    const int* cnt = (blockIdx.x == 0) ? cnt0 : cnt1;
    int* rp  = (blockIdx.x == 0) ? rp0  : rp1;
    int* cur = (blockIdx.x == 0) ? cur0 : cur1;
    int n    = (blockIdx.x == 0) ? n0   : n1;

    __shared__ int buf[1024];
    const int t = threadIdx.x;
    int carry = 0;
    for (int base = 0; base < n; base += 1024) {
        int i = base + t;
        int v = (i < n) ? cnt[i] : 0;
        buf[t] = v;
        __syncthreads();
        for (int off = 1; off < 1024; off <<= 1) {
            int add = (t >= off) ? buf[t - off] : 0;
            __syncthreads();
            buf[t] += add;
            __syncthreads();
        }
        int incl  = buf[t];
        int total = buf[1023];
        if (i < n) { int ex = carry + incl - v; rp[i] = ex; cur[i] = ex; }
        carry += total;
        __syncthreads();
    }
    if (t == 0) rp[n] = carry;
}

__global__ void k_scatter(const int* __restrict__ src, const int* __restrict__ dst,
                          int* __restrict__ cur, int* __restrict__ sl, int n) {
    for (int i = blockIdx.x * blockDim.x + threadIdx.x; i < n; i += gridDim.x * blockDim.x) {
        int p = atomicAdd(&cur[dst[i]], 1);
        sl[p] = src[i];
    }
}

// ---------------- input projection: out = GELU(X @ W + b), X:[M,128], W:[128,256] ----------------
// launch_bounds(256,4): 4 blocks/CU -> 128-VGPR cap; with #pragma unroll 2 the
// k-loop live set is ~80 VGPR, no scratch spill (R1: 256 VGPR + 2.7GB spill writes).
__global__ __launch_bounds__(256, 4) void k_proj(const float* __restrict__ X,
        const float* __restrict__ W, const float* __restrict__ b,
        float* __restrict__ out) {
    __shared__ __align__(16) float A[TM][DIN];
    const int t = threadIdx.x;
    const int w = t >> 6, l = t & 63;
    const int r0 = blockIdx.x * TM;
    const int c0 = 4 * l;

    #pragma unroll
    for (int i = 0; i < 4; ++i) {
        int r = w + 4 * i;
        const float2 v = *(const float2*)&X[(size_t)(r0 + r) * DIN + 2 * l];
        *(float2*)&A[r][2 * l] = v;
    }
    __syncthreads();

    f4 acc[4] = {{0,0,0,0},{0,0,0,0},{0,0,0,0},{0,0,0,0}};
    #pragma unroll 2
    for (int k = 0; k < DIN; k += 4) {
        f4 w0 = *(const f4*)&W[(size_t)(k + 0) * HD + c0];
        f4 w1 = *(const f4*)&W[(size_t)(k + 1) * HD + c0];
        f4 w2 = *(const f4*)&W[(size_t)(k + 2) * HD + c0];
        f4 w3 = *(const f4*)&W[(size_t)(k + 3) * HD + c0];
        #pragma unroll
        for (int i = 0; i < 4; ++i) {
            f4 av = *(const f4*)&A[4 * w + i][k];
            acc[i] += av.x * w0 + av.y * w1 + av.z * w2 + av.w * w3;
        }
    }
    f4 bias = *(const f4*)&b[c0];
    #pragma unroll
    for (int i = 0; i < 4; ++i) {
        f4 v = acc[i] + bias;
        v.x = gelu_f(v.x); v.y = gelu_f(v.y); v.z = gelu_f(v.z); v.w = gelu_f(v.w);
        *(f4*)&out[(size_t)(r0 + 4 * w + i) * HD + c0] = v;
    }
}

// ---------------- SAGE conv: out = GELU(mean_gather(hsrc) @ Wl + bl + hdst @ Wr) ----------------
__global__ __launch_bounds__(256, 4) void k_conv(const float* __restrict__ hsrc,
        const float* __restrict__ hdst, const int* __restrict__ rp, const int* __restrict__ sl,
        const float* __restrict__ Wl, const float* __restrict__ bl, const float* __restrict__ Wr,
        float* __restrict__ out) {
    __shared__ __align__(16) float A[TM][2 * HD];  // [r][0..255]=agg, [r][256..511]=root
    const int t = threadIdx.x;
    const int w = t >> 6, l = t & 63;
    const int r0 = blockIdx.x * TM;
    const int c0 = 4 * l;

    // stage: fused CSR mean-gather + root copy. wave w handles rows w, w+4, w+8, w+12
    #pragma unroll 1
    for (int i = 0; i < 4; ++i) {
        int r = w + 4 * i;
        int gr = r0 + r;
        f4 acc = {0, 0, 0, 0};
        int beg = rp[gr], end = rp[gr + 1];
        int e = beg;
        #pragma unroll 1
        for (; e + 4 <= end; e += 4) {   // 4 outstanding loads to hide L3 latency
            int s0 = sl[e], s1 = sl[e + 1], s2 = sl[e + 2], s3 = sl[e + 3];
            f4 v0 = *(const f4*)&hsrc[(size_t)s0 * HD + c0];
            f4 v1 = *(const f4*)&hsrc[(size_t)s1 * HD + c0];
            f4 v2 = *(const f4*)&hsrc[(size_t)s2 * HD + c0];
            f4 v3 = *(const f4*)&hsrc[(size_t)s3 * HD + c0];
            acc += (v0 + v1) + (v2 + v3);
        }
        #pragma unroll 1
        for (; e < end; ++e)
            acc += *(const f4*)&hsrc[(size_t)sl[e] * HD + c0];
        float inv = 1.0f / fmaxf((float)(end - beg), 1.0f);
        acc *= inv;
        *(f4*)&A[r][c0] = acc;
        *(f4*)&A[r][HD + c0] = *(const f4*)&hdst[(size_t)gr * HD + c0];
    }
    __syncthreads();

    // GEMM: thread (w,l) computes rows 4w..4w+3 x cols 4l..4l+3, K=512
    f4 acc[4] = {{0,0,0,0},{0,0,0,0},{0,0,0,0},{0,0,0,0}};
    #pragma unroll 2
    for (int k = 0; k < HD; k += 4) {
        f4 w0 = *(const f4*)&Wl[(size_t)(k + 0) * HD + c0];
        f4 w1 = *(const f4*)&Wl[(size_t)(k + 1) * HD + c0];
        f4 w2 = *(const f4*)&Wl[(size_t)(k + 2) * HD + c0];
        f4 w3 = *(const f4*)&Wl[(size_t)(k + 3) * HD + c0];
        #pragma unroll
        for (int i = 0; i < 4; ++i) {
            f4 av = *(const f4*)&A[4 * w + i][k];
            acc[i] += av.x * w0 + av.y * w1 + av.z * w2 + av.w * w3;
        }
    }
    #pragma unroll 2
    for (int k = 0; k < HD; k += 4) {
        f4 w0 = *(const f4*)&Wr[(size_t)(k + 0) * HD + c0];
        f4 w1 = *(const f4*)&Wr[(size_t)(k + 1) * HD + c0];
        f4 w2 = *(const f4*)&Wr[(size_t)(k + 2) * HD + c0];
        f4 w3 = *(const f4*)&Wr[(size_t)(k + 3) * HD + c0];
        #pragma unroll
        for (int i = 0; i < 4; ++i) {
            f4 av = *(const f4*)&A[4 * w + i][HD + k];
            acc[i] += av.x * w0 + av.y * w1 + av.z * w2 + av.w * w3;
        }
    }
    f4 bias = *(const f4*)&bl[c0];
    #pragma unroll
    for (int i = 0; i < 4; ++i) {
        f4 v = acc[i] + bias;
        v.x = gelu_f(v.x); v.y = gelu_f(v.y); v.z = gelu_f(v.z); v.w = gelu_f(v.w);
        *(f4*)&out[(size_t)(r0 + 4 * w + i) * HD + c0] = v;
    }
}

// ---------------- head: out = LayerNorm(H @ W + b) * g + b2 ----------------
__global__ __launch_bounds__(256, 4) void k_head(const float* __restrict__ Hin,
        const float* __restrict__ W, const float* __restrict__ b,
        const float* __restrict__ g, const float* __restrict__ b2,
        float* __restrict__ out) {
    __shared__ __align__(16) float A[TM][HD];
    const int t = threadIdx.x;
    const int w = t >> 6, l = t & 63;
    const int r0 = blockIdx.x * TM;
    const int c0 = 4 * l;

    #pragma unroll
    for (int i = 0; i < 4; ++i) {
        int r = w + 4 * i;
        *(f4*)&A[r][c0] = *(const f4*)&Hin[(size_t)(r0 + r) * HD + c0];
    }
    __syncthreads();

    f4 acc[4] = {{0,0,0,0},{0,0,0,0},{0,0,0,0},{0,0,0,0}};
    #pragma unroll 2
    for (int k = 0; k < HD; k += 4) {
        f4 w0 = *(const f4*)&W[(size_t)(k + 0) * HD + c0];
        f4 w1 = *(const f4*)&W[(size_t)(k + 1) * HD + c0];
        f4 w2 = *(const f4*)&W[(size_t)(k + 2) * HD + c0];
        f4 w3 = *(const f4*)&W[(size_t)(k + 3) * HD + c0];
        #pragma unroll
        for (int i = 0; i < 4; ++i) {
            f4 av = *(const f4*)&A[4 * w + i][k];
            acc[i] += av.x * w0 + av.y * w1 + av.z * w2 + av.w * w3;
        }
    }

    f4 bias = *(const f4*)&b[c0];
    f4 gv   = *(const f4*)&g[c0];
    f4 bv   = *(const f4*)&b2[c0];
    #pragma unroll
    for (int i = 0; i < 4; ++i) {
        f4 v = acc[i] + bias;
        float s = v.x + v.y + v.z + v.w;
        #pragma unroll
        for (int off = 32; off > 0; off >>= 1) s += __shfl_xor(s, off, 64);
        float mu = s * (1.0f / HD);
        f4 d = v - mu;
        float q = d.x * d.x + d.y * d.y + d.z * d.z + d.w * d.w;
        #pragma unroll
        for (int off = 32; off > 0; off >>= 1) q += __shfl_xor(q, off, 64);
        float rs = rsqrtf(q * (1.0f / HD) + 1e-5f);
        f4 o = d * rs * gv + bv;
        *(f4*)&out[(size_t)(r0 + 4 * w + i) * HD + c0] = o;
    }
}

extern "C" void kernel_launch(void* const* d_in, const int* in_sizes, int n_in,
                              void* d_out, int out_size, void* d_ws, size_t ws_size,
                              hipStream_t stream) {
    const float* x_user     = (const float*)d_in[0];
    const float* x_item     = (const float*)d_in[1];
    const int*   ei_ui_src  = (const int*)d_in[2];
    const int*   ei_ui_dst  = (const int*)d_in[3];
    const int*   ei_iu_src  = (const int*)d_in[4];
    const int*   ei_iu_dst  = (const int*)d_in[5];
    const float* lin_user_W = (const float*)d_in[6];
    const float* lin_user_b = (const float*)d_in[7];
    const float* lin_item_W = (const float*)d_in[8];
    const float* lin_item_b = (const float*)d_in[9];
    const float* c0_ui_Wl = (const float*)d_in[10];
    const float* c0_ui_bl = (const float*)d_in[11];
    const float* c0_ui_Wr = (const float*)d_in[12];
    const float* c0_iu_Wl = (const float*)d_in[13];
    const float* c0_iu_bl = (const float*)d_in[14];
    const float* c0_iu_Wr = (const float*)d_in[15];
    const float* c1_ui_Wl = (const float*)d_in[16];
    const float* c1_ui_bl = (const float*)d_in[17];
    const float* c1_ui_Wr = (const float*)d_in[18];
    const float* c1_iu_Wl = (const float*)d_in[19];
    const float* c1_iu_bl = (const float*)d_in[20];
    const float* c1_iu_Wr = (const float*)d_in[21];
    const float* out_user_W = (const float*)d_in[22];
    const float* out_user_b = (const float*)d_in[23];
    const float* out_item_W = (const float*)d_in[24];
    const float* out_item_b = (const float*)d_in[25];
    const float* ln_user_g  = (const float*)d_in[26];
    const float* ln_user_b2 = (const float*)d_in[27];
    const float* ln_item_g  = (const float*)d_in[28];
    const float* ln_item_b2 = (const float*)d_in[29];

    char* ws = (char*)d_ws;
    size_t off = 0;
    auto alloc = [&](size_t bytes) -> void* {
        void* p = ws + off;
        off += (bytes + 255) & ~(size_t)255;
        return p;
    };
    float* Au   = (float*)alloc((size_t)NUSER * HD * 4);   // h_user ping
    float* Ai   = (float*)alloc((size_t)NITEM * HD * 4);   // h_item ping
    int* rp_i   = (int*)alloc((NITEM + 1) * 4);            // CSR row_ptr, dst=item (ui edges)
    int* rp_u   = (int*)alloc((NUSER + 1) * 4);            // CSR row_ptr, dst=user (iu edges)
    int* cur_i  = (int*)alloc(NITEM * 4);
    int* cur_u  = (int*)alloc(NUSER * 4);
    int* cnt_i  = (int*)alloc(NITEM * 4);
    int* cnt_u  = (int*)alloc(NUSER * 4);
    int* sl_ui  = (int*)alloc((size_t)NEDGE * 4);          // src (user) sorted by dst item
    int* sl_iu  = (int*)alloc((size_t)NEDGE * 4);          // src (item) sorted by dst user

    // h pong buffers live in d_out (fully overwritten by the heads at the end)
    float* Bu = (float*)d_out;
    float* Bi = (float*)d_out + (size_t)NUSER * HD;

    // ---- CSR build ----
    hipMemsetAsync(cnt_i, 0, NITEM * 4, stream);
    hipMemsetAsync(cnt_u, 0, NUSER * 4, stream);
    k_hist<<<1024, 256, 0, stream>>>(ei_ui_dst, cnt_i, NEDGE);
    k_hist<<<1024, 256, 0, stream>>>(ei_iu_dst, cnt_u, NEDGE);
    k_scan2<<<2, 1024, 0, stream>>>(cnt_i, rp_i, cur_i, NITEM, cnt_u, rp_u, cur_u, NUSER);
    k_scatter<<<1024, 256, 0, stream>>>(ei_ui_src, ei_ui_dst, cur_i, sl_ui, NEDGE);
    k_scatter<<<1024, 256, 0, stream>>>(ei_iu_src, ei_iu_dst, cur_u, sl_iu, NEDGE);

    // ---- input projections ----
    k_proj<<<NUSER / TM, 256, 0, stream>>>(x_user, lin_user_W, lin_user_b, Au);
    k_proj<<<NITEM / TM, 256, 0, stream>>>(x_item, lin_item_W, lin_item_b, Ai);

    // ---- layer 0 (reads A*, writes B*) ----
    k_conv<<<NITEM / TM, 256, 0, stream>>>(Au, Ai, rp_i, sl_ui, c0_ui_Wl, c0_ui_bl, c0_ui_Wr, Bi);
    k_conv<<<NUSER / TM, 256, 0, stream>>>(Ai, Au, rp_u, sl_iu, c0_iu_Wl, c0_iu_bl, c0_iu_Wr, Bu);

    // ---- layer 1 (reads B*, writes A*) ----
    k_conv<<<NITEM / TM, 256, 0, stream>>>(Bu, Bi, rp_i, sl_ui, c1_ui_Wl, c1_ui_bl, c1_ui_Wr, Ai);
    k_conv<<<NUSER / TM, 256, 0, stream>>>(Bi, Bu, rp_u, sl_iu, c1_iu_Wl, c1_iu_bl, c1_iu_Wr, Au);

    // ---- heads + LayerNorm (reads A*, writes d_out; B* no longer needed) ----
    k_head<<<NUSER / TM, 256, 0, stream>>>(Au, out_user_W, out_user_b, ln_user_g, ln_user_b2,
                                           (float*)d_out);
    k_head<<<NITEM / TM, 256, 0, stream>>>(Ai, out_item_W, out_item_b, ln_item_g, ln_item_b2,
                                           (float*)d_out + (size_t)NUSER * HD);
}

// Round 3
// 1449.517 us; speedup vs baseline: 4.4457x; 2.5789x over previous
//
#include <hip/hip_runtime.h>
#include <math.h>

#define NUSER 100000
#define NITEM 100000
#define NEDGE 800000
#define DIN 128
#define HD 256
#define BM 64
#define BK 64

typedef __attribute__((ext_vector_type(8))) short bf16x8;
typedef __attribute__((ext_vector_type(4))) float f32x4;

__device__ __forceinline__ float gelu_f(float x) {
    return 0.5f * x * (1.0f + erff(x * 0.70710678118654752440f));
}
__device__ __forceinline__ unsigned short f2bf(float f) {
    union { unsigned int i; float f; } v; v.f = f;
    unsigned int r = (v.i + 0x7FFFu + ((v.i >> 16) & 1u)) >> 16;  // RNE
    return (unsigned short)r;
}
__device__ __forceinline__ float bflo(unsigned int p) {  // low bf16 of packed pair
    union { unsigned int i; float f; } v; v.i = p << 16; return v.f;
}
__device__ __forceinline__ float bfhi(unsigned int p) {  // high bf16 of packed pair
    union { unsigned int i; float f; } v; v.i = p & 0xFFFF0000u; return v.f;
}

// ---------------- CSR build ----------------
__global__ void k_hist(const int* __restrict__ dst, int* __restrict__ cnt, int n) {
    for (int i = blockIdx.x * blockDim.x + threadIdx.x; i < n; i += gridDim.x * blockDim.x)
        atomicAdd(&cnt[dst[i]], 1);
}

__global__ __launch_bounds__(1024) void k_scan2(
    const int* __restrict__ cnt0, int* __restrict__ rp0, int* __restrict__ cur0, int n0,
    const int* __restrict__ cnt1, int* __restrict__ rp1, int* __restrict__ cur1, int n1) {
    const int* cnt = (blockIdx.x == 0) ? cnt0 : cnt1;
    int* rp  = (blockIdx.x == 0) ? rp0  : rp1;
    int* cur = (blockIdx.x == 0) ? cur0 : cur1;
    int n    = (blockIdx.x == 0) ? n0   : n1;
    __shared__ int buf[1024];
    const int t = threadIdx.x;
    int carry = 0;
    for (int base = 0; base < n; base += 1024) {
        int i = base + t;
        int v = (i < n) ? cnt[i] : 0;
        buf[t] = v;
        __syncthreads();
        for (int off = 1; off < 1024; off <<= 1) {
            int add = (t >= off) ? buf[t - off] : 0;
            __syncthreads();
            buf[t] += add;
            __syncthreads();
        }
        int incl = buf[t], total = buf[1023];
        if (i < n) { int ex = carry + incl - v; rp[i] = ex; cur[i] = ex; }
        carry += total;
        __syncthreads();
    }
    if (t == 0) rp[n] = carry;
}

__global__ void k_scatter(const int* __restrict__ src, const int* __restrict__ dst,
                          int* __restrict__ cur, int* __restrict__ sl, int n) {
    for (int i = blockIdx.x * blockDim.x + threadIdx.x; i < n; i += gridDim.x * blockDim.x) {
        int p = atomicAdd(&cur[dst[i]], 1);
        sl[p] = src[i];
    }
}

// ---------------- dtype prep ----------------
// f32 -> bf16 elementwise, 4 elems/thread
__global__ void k_cvt(const float* __restrict__ src, unsigned short* __restrict__ dst, int n4) {
    int i = blockIdx.x * blockDim.x + threadIdx.x;
    if (i < n4) {
        const float4 v = *(const float4*)(src + 4 * (size_t)i);
        unsigned int lo = (unsigned int)f2bf(v.x) | ((unsigned int)f2bf(v.y) << 16);
        unsigned int hi = (unsigned int)f2bf(v.z) | ((unsigned int)f2bf(v.w) << 16);
        uint2 o = {lo, hi};
        *(uint2*)(dst + 4 * (size_t)i) = o;
    }
}

// W f32 [K,256] -> WT bf16 [256][Kt] (transposed, at k-offset koff)
__global__ void k_cvtT(const float* __restrict__ src, unsigned short* __restrict__ dst,
                       int K, int Kt, int koff) {
    int i = blockIdx.x * blockDim.x + threadIdx.x;
    if (i < K * 256) {
        int k = i >> 8, n = i & 255;
        dst[(size_t)n * Kt + koff + k] = f2bf(src[i]);
    }
}

// ---------------- CSR mean gather: agg[row] = mean_{s in N(row)} h[s], bf16 ----------------
// one wave per row; lane covers 4 cols (8B); 4 edges in flight for L2/L3 latency
__global__ __launch_bounds__(256, 4) void k_gather(
    const unsigned short* __restrict__ h, const int* __restrict__ rp,
    const int* __restrict__ sl, unsigned short* __restrict__ agg, int nrows) {
    const int wv = threadIdx.x >> 6, l = threadIdx.x & 63;
    for (int row = blockIdx.x * 4 + wv; row < nrows; row += gridDim.x * 4) {
        int beg = rp[row], end = rp[row + 1];
        float a0 = 0, a1 = 0, a2 = 0, a3 = 0;
        int e = beg;
        #pragma unroll 1
        for (; e + 4 <= end; e += 4) {
            int s0 = sl[e], s1 = sl[e + 1], s2 = sl[e + 2], s3 = sl[e + 3];
            uint2 v0 = *(const uint2*)(h + (size_t)s0 * HD + 4 * l);
            uint2 v1 = *(const uint2*)(h + (size_t)s1 * HD + 4 * l);
            uint2 v2 = *(const uint2*)(h + (size_t)s2 * HD + 4 * l);
            uint2 v3 = *(const uint2*)(h + (size_t)s3 * HD + 4 * l);
            a0 += bflo(v0.x) + bflo(v1.x) + bflo(v2.x) + bflo(v3.x);
            a1 += bfhi(v0.x) + bfhi(v1.x) + bfhi(v2.x) + bfhi(v3.x);
            a2 += bflo(v0.y) + bflo(v1.y) + bflo(v2.y) + bflo(v3.y);
            a3 += bfhi(v0.y) + bfhi(v1.y) + bfhi(v2.y) + bfhi(v3.y);
        }
        #pragma unroll 1
        for (; e < end; ++e) {
            uint2 v = *(const uint2*)(h + (size_t)sl[e] * HD + 4 * l);
            a0 += bflo(v.x); a1 += bfhi(v.x); a2 += bflo(v.y); a3 += bfhi(v.y);
        }
        float inv = 1.0f / fmaxf((float)(end - beg), 1.0f);
        unsigned int lo = (unsigned int)f2bf(a0 * inv) | ((unsigned int)f2bf(a1 * inv) << 16);
        unsigned int hi = (unsigned int)f2bf(a2 * inv) | ((unsigned int)f2bf(a3 * inv) << 16);
        uint2 o = {lo, hi};
        *(uint2*)(agg + (size_t)row * HD + 4 * l) = o;
    }
}

// ---------------- MFMA GEMM, GELU epilogue, bf16 out ----------------
// C[M,256] = GELU([A1|A2] @ W + b). A split at k=K1 (A2 may be null / K2=0).
// WT is [256][Kt] bf16 (pre-transposed weights). BM=64, BN=256 (4 waves x 64 cols), BK=64.
// LDS xor-swizzle: 16B unit sg of row r lives at r*128 + ((sg^(r&7))*16) -> conflict-free
// b128 reads (each 16-lane group spans all 8 bank-quads) and writes.
__global__ __launch_bounds__(256, 3) void k_mm_gelu(
    const unsigned short* __restrict__ A1, const unsigned short* __restrict__ A2,
    int K1, int K2,
    const unsigned short* __restrict__ WT, const float* __restrict__ bias,
    unsigned short* __restrict__ out, int M) {
    const int Kt = K1 + K2;
    __shared__ char sm[BM * 128 + 256 * 128];  // A 8KB + B 32KB
    char* sA = sm;
    char* sB = sm + BM * 128;
    const int t = threadIdx.x;
    const int wv = t >> 6, l = t & 63;
    const int l15 = l & 15, lq = l >> 4;
    const int r0 = blockIdx.x * BM;

    f32x4 acc[4][4];
    #pragma unroll
    for (int i = 0; i < 4; ++i)
        #pragma unroll
        for (int j = 0; j < 4; ++j) acc[i][j] = (f32x4){0, 0, 0, 0};

    const int nchunks = Kt / BK;
    #pragma unroll 1
    for (int c = 0; c < nchunks; ++c) {
        const int k0 = c * BK;
        const unsigned short* Ap; int kloc, strideA;
        if (k0 < K1) { Ap = A1; kloc = k0;      strideA = K1; }
        else         { Ap = A2; kloc = k0 - K1; strideA = K2; }
        __syncthreads();  // WAR: prev iter's frag reads before restage
        #pragma unroll
        for (int j = 0; j < 2; ++j) {  // A: 512 16B units
            int u = t + 256 * j;
            int r = u >> 3, sg = u & 7;
            int gr = r0 + r; if (gr >= M) gr = M - 1;
            uint4 v = *(const uint4*)(Ap + (size_t)gr * strideA + kloc + sg * 8);
            *(uint4*)(sA + r * 128 + ((sg ^ (r & 7)) << 4)) = v;
        }
        #pragma unroll
        for (int j = 0; j < 8; ++j) {  // B: 2048 16B units
            int u = t + 256 * j;
            int n = u >> 3, sg = u & 7;
            uint4 v = *(const uint4*)(WT + (size_t)n * Kt + k0 + sg * 8);
            *(uint4*)(sB + n * 128 + ((sg ^ (n & 7)) << 4)) = v;
        }
        __syncthreads();
        #pragma unroll
        for (int ks = 0; ks < 2; ++ks) {
            bf16x8 af[4], bfr[4];
            int sg = ks * 4 + lq;
            #pragma unroll
            for (int mt = 0; mt < 4; ++mt) {
                int m = mt * 16 + l15;
                af[mt] = *(const bf16x8*)(sA + m * 128 + ((sg ^ (m & 7)) << 4));
            }
            #pragma unroll
            for (int nt = 0; nt < 4; ++nt) {
                int n = wv * 64 + nt * 16 + l15;
                bfr[nt] = *(const bf16x8*)(sB + n * 128 + ((sg ^ (n & 7)) << 4));
            }
            #pragma unroll
            for (int mt = 0; mt < 4; ++mt)
                #pragma unroll
                for (int nt = 0; nt < 4; ++nt)
                    acc[mt][nt] = __builtin_amdgcn_mfma_f32_16x16x32_bf16(
                        af[mt], bfr[nt], acc[mt][nt], 0, 0, 0);
        }
    }
    // epilogue: C/D layout col=lane&15, row=(lane>>4)*4+reg
    #pragma unroll
    for (int nt = 0; nt < 4; ++nt) {
        int col = wv * 64 + nt * 16 + l15;
        float bs = bias[col];
        #pragma unroll
        for (int mt = 0; mt < 4; ++mt) {
            int rowb = r0 + mt * 16 + lq * 4;
            #pragma unroll
            for (int rg = 0; rg < 4; ++rg) {
                int row = rowb + rg;
                if (row < M)
                    out[(size_t)row * HD + col] = f2bf(gelu_f(acc[mt][nt][rg] + bs));
            }
        }
    }
}

// ---------------- MFMA GEMM + LayerNorm epilogue, f32 out ----------------
// Each wave owns 16 rows x all 256 cols so LN row-reduction is wave-local
// (shuffle-xor over the 16-lane column group).
__global__ __launch_bounds__(256, 3) void k_mm_ln(
    const unsigned short* __restrict__ A, const unsigned short* __restrict__ WT,
    const float* __restrict__ bias, const float* __restrict__ g,
    const float* __restrict__ b2, float* __restrict__ out, int M) {
    const int Kt = HD;
    __shared__ char sm[BM * 128 + 256 * 128];
    char* sA = sm;
    char* sB = sm + BM * 128;
    const int t = threadIdx.x;
    const int wv = t >> 6, l = t & 63;
    const int l15 = l & 15, lq = l >> 4;
    const int r0 = blockIdx.x * BM;

    f32x4 acc[16];
    #pragma unroll
    for (int i = 0; i < 16; ++i) acc[i] = (f32x4){0, 0, 0, 0};

    #pragma unroll 1
    for (int c = 0; c < Kt / BK; ++c) {
        const int k0 = c * BK;
        __syncthreads();
        #pragma unroll
        for (int j = 0; j < 2; ++j) {
            int u = t + 256 * j;
            int r = u >> 3, sg = u & 7;
            int gr = r0 + r; if (gr >= M) gr = M - 1;
            uint4 v = *(const uint4*)(A + (size_t)gr * Kt + k0 + sg * 8);
            *(uint4*)(sA + r * 128 + ((sg ^ (r & 7)) << 4)) = v;
        }
        #pragma unroll
        for (int j = 0; j < 8; ++j) {
            int u = t + 256 * j;
            int n = u >> 3, sg = u & 7;
            uint4 v = *(const uint4*)(WT + (size_t)n * Kt + k0 + sg * 8);
            *(uint4*)(sB + n * 128 + ((sg ^ (n & 7)) << 4)) = v;
        }
        __syncthreads();
        #pragma unroll
        for (int ks = 0; ks < 2; ++ks) {
            int sg = ks * 4 + lq;
            int m = wv * 16 + l15;  // this wave's 16 rows
            bf16x8 af = *(const bf16x8*)(sA + m * 128 + ((sg ^ (m & 7)) << 4));
            #pragma unroll
            for (int nt = 0; nt < 16; ++nt) {
                int n = nt * 16 + l15;
                bf16x8 bfr = *(const bf16x8*)(sB + n * 128 + ((sg ^ (n & 7)) << 4));
                acc[nt] = __builtin_amdgcn_mfma_f32_16x16x32_bf16(af, bfr, acc[nt], 0, 0, 0);
            }
        }
    }
    // bias + LN. Lane holds rows (wv*16 + lq*4 + rg), cols (nt*16 + l15).
    #pragma unroll
    for (int nt = 0; nt < 16; ++nt) {
        float bs = bias[nt * 16 + l15];
        #pragma unroll
        for (int rg = 0; rg < 4; ++rg) acc[nt][rg] += bs;
    }
    float s0 = 0, s1 = 0, s2 = 0, s3 = 0;
    #pragma unroll
    for (int nt = 0; nt < 16; ++nt) { s0 += acc[nt][0]; s1 += acc[nt][1]; s2 += acc[nt][2]; s3 += acc[nt][3]; }
    #pragma unroll
    for (int off = 1; off < 16; off <<= 1) {
        s0 += __shfl_xor(s0, off, 64); s1 += __shfl_xor(s1, off, 64);
        s2 += __shfl_xor(s2, off, 64); s3 += __shfl_xor(s3, off, 64);
    }
    const float mu0 = s0 * (1.0f / HD), mu1 = s1 * (1.0f / HD),
                mu2 = s2 * (1.0f / HD), mu3 = s3 * (1.0f / HD);
    float q0 = 0, q1 = 0, q2 = 0, q3 = 0;
    #pragma unroll
    for (int nt = 0; nt < 16; ++nt) {
        float d0 = acc[nt][0] - mu0, d1 = acc[nt][1] - mu1,
              d2 = acc[nt][2] - mu2, d3 = acc[nt][3] - mu3;
        q0 += d0 * d0; q1 += d1 * d1; q2 += d2 * d2; q3 += d3 * d3;
    }
    #pragma unroll
    for (int off = 1; off < 16; off <<= 1) {
        q0 += __shfl_xor(q0, off, 64); q1 += __shfl_xor(q1, off, 64);
        q2 += __shfl_xor(q2, off, 64); q3 += __shfl_xor(q3, off, 64);
    }
    const float rs0 = rsqrtf(q0 * (1.0f / HD) + 1e-5f), rs1 = rsqrtf(q1 * (1.0f / HD) + 1e-5f),
                rs2 = rsqrtf(q2 * (1.0f / HD) + 1e-5f), rs3 = rsqrtf(q3 * (1.0f / HD) + 1e-5f);
    const int rowb = r0 + wv * 16 + lq * 4;
    #pragma unroll
    for (int nt = 0; nt < 16; ++nt) {
        int col = nt * 16 + l15;
        float gg = g[col], bb = b2[col];
        float mu[4] = {mu0, mu1, mu2, mu3};
        float rs[4] = {rs0, rs1, rs2, rs3};
        #pragma unroll
        for (int rg = 0; rg < 4; ++rg) {
            int row = rowb + rg;
            if (row < M)
                out[(size_t)row * HD + col] = (acc[nt][rg] - mu[rg]) * rs[rg] * gg + bb;
        }
    }
}

extern "C" void kernel_launch(void* const* d_in, const int* in_sizes, int n_in,
                              void* d_out, int out_size, void* d_ws, size_t ws_size,
                              hipStream_t stream) {
    const float* x_user     = (const float*)d_in[0];
    const float* x_item     = (const float*)d_in[1];
    const int*   ei_ui_src  = (const int*)d_in[2];
    const int*   ei_ui_dst  = (const int*)d_in[3];
    const int*   ei_iu_src  = (const int*)d_in[4];
    const int*   ei_iu_dst  = (const int*)d_in[5];
    const float* lin_user_W = (const float*)d_in[6];
    const float* lin_user_b = (const float*)d_in[7];
    const float* lin_item_W = (const float*)d_in[8];
    const float* lin_item_b = (const float*)d_in[9];
    const float* c0_ui_Wl = (const float*)d_in[10];
    const float* c0_ui_bl = (const float*)d_in[11];
    const float* c0_ui_Wr = (const float*)d_in[12];
    const float* c0_iu_Wl = (const float*)d_in[13];
    const float* c0_iu_bl = (const float*)d_in[14];
    const float* c0_iu_Wr = (const float*)d_in[15];
    const float* c1_ui_Wl = (const float*)d_in[16];
    const float* c1_ui_bl = (const float*)d_in[17];
    const float* c1_ui_Wr = (const float*)d_in[18];
    const float* c1_iu_Wl = (const float*)d_in[19];
    const float* c1_iu_bl = (const float*)d_in[20];
    const float* c1_iu_Wr = (const float*)d_in[21];
    const float* out_user_W = (const float*)d_in[22];
    const float* out_user_b = (const float*)d_in[23];
    const float* out_item_W = (const float*)d_in[24];
    const float* out_item_b = (const float*)d_in[25];
    const float* ln_user_g  = (const float*)d_in[26];
    const float* ln_user_b2 = (const float*)d_in[27];
    const float* ln_item_g  = (const float*)d_in[28];
    const float* ln_item_b2 = (const float*)d_in[29];

    char* ws = (char*)d_ws;
    size_t off = 0;
    auto alloc = [&](size_t bytes) -> void* {
        void* p = ws + off;
        off += (bytes + 255) & ~(size_t)255;
        return p;
    };
    typedef unsigned short u16;
    u16* xb_u = (u16*)alloc((size_t)NUSER * DIN * 2);
    u16* xb_i = (u16*)alloc((size_t)NITEM * DIN * 2);
    u16* hu_a = (u16*)alloc((size_t)NUSER * HD * 2);
    u16* hi_a = (u16*)alloc((size_t)NITEM * HD * 2);
    u16* agg  = (u16*)alloc((size_t)NUSER * HD * 2);   // shared: convs run sequentially
    u16* WT_lu   = (u16*)alloc((size_t)HD * DIN * 2);
    u16* WT_li   = (u16*)alloc((size_t)HD * DIN * 2);
    u16* WT_c0ui = (u16*)alloc((size_t)HD * 2 * HD * 2);
    u16* WT_c0iu = (u16*)alloc((size_t)HD * 2 * HD * 2);
    u16* WT_c1ui = (u16*)alloc((size_t)HD * 2 * HD * 2);
    u16* WT_c1iu = (u16*)alloc((size_t)HD * 2 * HD * 2);
    u16* WT_ou   = (u16*)alloc((size_t)HD * HD * 2);
    u16* WT_oi   = (u16*)alloc((size_t)HD * HD * 2);
    int* rp_i  = (int*)alloc((NITEM + 1) * 4);
    int* rp_u  = (int*)alloc((NUSER + 1) * 4);
    int* cur_i = (int*)alloc(NITEM * 4);
    int* cur_u = (int*)alloc(NUSER * 4);
    int* cnt_i = (int*)alloc(NITEM * 4);
    int* cnt_u = (int*)alloc(NUSER * 4);
    int* sl_ui = (int*)alloc((size_t)NEDGE * 4);
    int* sl_iu = (int*)alloc((size_t)NEDGE * 4);

    // h pong buffers (bf16) live in d_out's 204.8MB; heads overwrite d_out last
    u16* hu_b = (u16*)d_out;
    u16* hi_b = (u16*)d_out + (size_t)NUSER * HD;

    const int MMG = (NUSER + BM - 1) / BM;  // == for NITEM too

    // ---- CSR build ----
    hipMemsetAsync(cnt_i, 0, NITEM * 4, stream);
    hipMemsetAsync(cnt_u, 0, NUSER * 4, stream);
    k_hist<<<1024, 256, 0, stream>>>(ei_ui_dst, cnt_i, NEDGE);
    k_hist<<<1024, 256, 0, stream>>>(ei_iu_dst, cnt_u, NEDGE);
    k_scan2<<<2, 1024, 0, stream>>>(cnt_i, rp_i, cur_i, NITEM, cnt_u, rp_u, cur_u, NUSER);
    k_scatter<<<1024, 256, 0, stream>>>(ei_ui_src, ei_ui_dst, cur_i, sl_ui, NEDGE);
    k_scatter<<<1024, 256, 0, stream>>>(ei_iu_src, ei_iu_dst, cur_u, sl_iu, NEDGE);

    // ---- dtype prep (bf16 x, transposed bf16 weights) ----
    k_cvt<<<(NUSER * DIN / 4 + 255) / 256, 256, 0, stream>>>(x_user, xb_u, NUSER * DIN / 4);
    k_cvt<<<(NITEM * DIN / 4 + 255) / 256, 256, 0, stream>>>(x_item, xb_i, NITEM * DIN / 4);
    k_cvtT<<<DIN, 256, 0, stream>>>(lin_user_W, WT_lu, DIN, DIN, 0);
    k_cvtT<<<DIN, 256, 0, stream>>>(lin_item_W, WT_li, DIN, DIN, 0);
    k_cvtT<<<HD, 256, 0, stream>>>(c0_ui_Wl, WT_c0ui, HD, 2 * HD, 0);
    k_cvtT<<<HD, 256, 0, stream>>>(c0_ui_Wr, WT_c0ui, HD, 2 * HD, HD);
    k_cvtT<<<HD, 256, 0, stream>>>(c0_iu_Wl, WT_c0iu, HD, 2 * HD, 0);
    k_cvtT<<<HD, 256, 0, stream>>>(c0_iu_Wr, WT_c0iu, HD, 2 * HD, HD);
    k_cvtT<<<HD, 256, 0, stream>>>(c1_ui_Wl, WT_c1ui, HD, 2 * HD, 0);
    k_cvtT<<<HD, 256, 0, stream>>>(c1_ui_Wr, WT_c1ui, HD, 2 * HD, HD);
    k_cvtT<<<HD, 256, 0, stream>>>(c1_iu_Wl, WT_c1iu, HD, 2 * HD, 0);
    k_cvtT<<<HD, 256, 0, stream>>>(c1_iu_Wr, WT_c1iu, HD, 2 * HD, HD);
    k_cvtT<<<HD, 256, 0, stream>>>(out_user_W, WT_ou, HD, HD, 0);
    k_cvtT<<<HD, 256, 0, stream>>>(out_item_W, WT_oi, HD, HD, 0);

    // ---- input projections ----
    k_mm_gelu<<<MMG, 256, 0, stream>>>(xb_u, (const u16*)nullptr, DIN, 0, WT_lu, lin_user_b, hu_a, NUSER);
    k_mm_gelu<<<MMG, 256, 0, stream>>>(xb_i, (const u16*)nullptr, DIN, 0, WT_li, lin_item_b, hi_a, NITEM);

    // ---- layer 0 ----
    k_gather<<<4096, 256, 0, stream>>>(hu_a, rp_i, sl_ui, agg, NITEM);
    k_mm_gelu<<<MMG, 256, 0, stream>>>(agg, hi_a, HD, HD, WT_c0ui, c0_ui_bl, hi_b, NITEM);
    k_gather<<<4096, 256, 0, stream>>>(hi_a, rp_u, sl_iu, agg, NUSER);
    k_mm_gelu<<<MMG, 256, 0, stream>>>(agg, hu_a, HD, HD, WT_c0iu, c0_iu_bl, hu_b, NUSER);

    // ---- layer 1 ----
    k_gather<<<4096, 256, 0, stream>>>(hu_b, rp_i, sl_ui, agg, NITEM);
    k_mm_gelu<<<MMG, 256, 0, stream>>>(agg, hi_b, HD, HD, WT_c1ui, c1_ui_bl, hi_a, NITEM);
    k_gather<<<4096, 256, 0, stream>>>(hi_b, rp_u, sl_iu, agg, NUSER);
    k_mm_gelu<<<MMG, 256, 0, stream>>>(agg, hu_b, HD, HD, WT_c1iu, c1_iu_bl, hu_a, NUSER);

    // ---- heads + LayerNorm (read ws, write d_out) ----
    k_mm_ln<<<MMG, 256, 0, stream>>>(hu_a, WT_ou, out_user_b, ln_user_g, ln_user_b2,
                                     (float*)d_out, NUSER);
    k_mm_ln<<<MMG, 256, 0, stream>>>(hi_a, WT_oi, out_item_b, ln_item_g, ln_item_b2,
                                     (float*)d_out + (size_t)NUSER * HD, NITEM);
}